// Round 7
// baseline (2071.445 us; speedup 1.0000x reference)
//
#include <hip/hip_runtime.h>
#include <hip/hip_bf16.h>
#include <type_traits>

#define DD    512
#define HH    8
#define HD    64
#define NLAYER 6
#define DFFN  2048
#define LATD  256
#define BB    4
#define LQQ   512
#define LCC   128

typedef unsigned short u16;
typedef __attribute__((ext_vector_type(8))) short bf16x8;
typedef __attribute__((ext_vector_type(4))) float f32x4;
typedef __attribute__((ext_vector_type(4))) unsigned short u16x4;

__device__ __forceinline__ u16 f2bf(float f) {
    __hip_bfloat16 h = __float2bfloat16(f);
    return __builtin_bit_cast(u16, h);
}
__device__ __forceinline__ float bf2f(u16 u) {
    return __uint_as_float(((unsigned int)u) << 16);
}

// ---------------------------------------------------------------------------
// MFMA bf16 GEMM, all operands bf16, B is [N][K] row-major.
// BK=64, LDS double-buffer + 2-slot register pipeline: loads for slab s+2
// issued in iter s, stored to LDS in iter s+1, consumed in iter s+2 -> the
// vmcnt wait is hidden behind a full iteration. One barrier per iter.
// MULTI: blockIdx.z selects (B,C) from up to 3 (fused QKV / KV); else
// z = zb*Hdim+zh batches with per-operand strides (also used for split-K:
// Hdim=nchunks, sAh/sBh = chunk K-offset, sCh=0, atomicf=1).
// atomicf: fp32 epilogue does atomicAdd into C (C pre-holds residual);
//          bias added by chunk zh==0 only.
// wt: transposed epilogue store C[gn*ldct + (gm>>wt_shift)*sbT + (gm&mask)]
//     (ushort4 over 4 consecutive m); v = alpha*acc + beta2*add2T.
// normal: v = alpha*acc + bias[n]; act==1 exact gelu; += res[(gm>>rs)*ldres+gn].
// ---------------------------------------------------------------------------
template<int BM, int BN, typename TC, bool MULTI>
__global__ __launch_bounds__(256)
void k_g(const u16* __restrict__ A, long long sAb, long long sAh, int lda,
         const u16* __restrict__ B1, const u16* __restrict__ B2_, const u16* __restrict__ B3_,
         long long sBb, long long sBh, int ldb,
         TC* __restrict__ C1, TC* __restrict__ C2_, TC* __restrict__ C3_,
         long long sCb, long long sCh, int ldc,
         int K, int Hdim, float alpha,
         const float* __restrict__ bias,
         const float* __restrict__ res, int ldres, int res_shift,
         float beta2, const u16* __restrict__ add2, long long s2b, long long s2h,
         int act, int atomicf, int wt_mask, int wt_shift, long long sbT, int ldct)
{
    constexpr int SK = 72;          // LDS row stride in u16 (144 B, 16B-aligned)
    constexpr int FM = BM / 32, FN = BN / 32;
    constexpr int PA = BM / 32, PB = BN / 32;   // uint4 loads per thread

    const int z = blockIdx.z;
    const u16* Bm;
    TC* C;
    int wt, zh = 0;
    if constexpr (MULTI) {
        Bm = (z == 0) ? B1 : ((z == 1) ? B2_ : B3_);
        C  = (z == 0) ? C1 : ((z == 1) ? C2_ : C3_);
        wt = (wt_mask >> z) & 1;
    } else {
        const int zb = z / Hdim;
        zh = z % Hdim;
        A += (size_t)(zb * sAb + zh * sAh);
        Bm = B1 + (size_t)(zb * sBb + zh * sBh);
        C  = C1 + (size_t)(zb * sCb + zh * sCh);
        if (add2) add2 += (size_t)(zb * s2b + zh * s2h);
        wt = wt_mask & 1;
    }

    __shared__ u16 Asm[2][BM * SK];
    __shared__ u16 Bsm[2][BN * SK];

    const int t    = threadIdx.x;
    const int wid  = t >> 6, lane = t & 63;
    const int q    = lane >> 4, c = lane & 15;
    const int wm   = (wid >> 1) * (BM / 2), wn = (wid & 1) * (BN / 2);
    const int m0   = blockIdx.y * BM, n0 = blockIdx.x * BN;

    f32x4 acc[FM][FN];
    #pragma unroll
    for (int i = 0; i < FM; i++)
        #pragma unroll
        for (int j = 0; j < FN; j++) acc[i][j] = (f32x4){0.f, 0.f, 0.f, 0.f};

    uint4 ra[2][PA], rb[2][PB];
    const int NI = K >> 6;

    auto loadg = [&](int slot, int kt) {
        #pragma unroll
        for (int p = 0; p < PA; p++) {
            const int idx = p * 256 + t, r = idx >> 3, kg = (idx & 7) << 3;
            ra[slot][p] = *(const uint4*)(A + (size_t)(m0 + r) * lda + kt + kg);
        }
        #pragma unroll
        for (int p = 0; p < PB; p++) {
            const int idx = p * 256 + t, r = idx >> 3, kg = (idx & 7) << 3;
            rb[slot][p] = *(const uint4*)(Bm + (size_t)(n0 + r) * ldb + kt + kg);
        }
    };
    auto store = [&](int buf, int slot) {
        #pragma unroll
        for (int p = 0; p < PA; p++) {
            const int idx = p * 256 + t, r = idx >> 3, kg = (idx & 7) << 3;
            *(uint4*)&Asm[buf][r * SK + kg] = ra[slot][p];
        }
        #pragma unroll
        for (int p = 0; p < PB; p++) {
            const int idx = p * 256 + t, r = idx >> 3, kg = (idx & 7) << 3;
            *(uint4*)&Bsm[buf][r * SK + kg] = rb[slot][p];
        }
    };

    loadg(0, 0);
    if (NI > 1) loadg(1, 64);
    store(0, 0);                    // waits only on slab-0 loads

    for (int it = 0; it < NI; it++) {
        __syncthreads();            // slab-it stores visible; buf nxt free
        const int cur = it & 1, nxt = cur ^ 1;
        if (it + 1 < NI) store(nxt, nxt);          // slab it+1 (slot (it+1)&1)
        if (it + 2 < NI) loadg(cur, (it + 2) << 6); // slab it+2 into freed slot
        #pragma unroll
        for (int s = 0; s < 2; s++) {
            bf16x8 af[FM], bfv[FN];
            #pragma unroll
            for (int fm = 0; fm < FM; fm++)
                af[fm] = *(const bf16x8*)&Asm[cur][(wm + fm * 16 + c) * SK + s * 32 + q * 8];
            #pragma unroll
            for (int fn = 0; fn < FN; fn++)
                bfv[fn] = *(const bf16x8*)&Bsm[cur][(wn + fn * 16 + c) * SK + s * 32 + q * 8];
            #pragma unroll
            for (int fm = 0; fm < FM; fm++)
                #pragma unroll
                for (int fn = 0; fn < FN; fn++)
                    acc[fm][fn] = __builtin_amdgcn_mfma_f32_16x16x32_bf16(
                        af[fm], bfv[fn], acc[fm][fn], 0, 0, 0);
        }
    }

    // ---- epilogue: C/D frag layout col=lane&15, row=quad*4+reg ----
    if (wt) {
        if constexpr (std::is_same<TC, u16>::value) {
            #pragma unroll
            for (int fm = 0; fm < FM; fm++) {
                const int gm0 = m0 + wm + fm * 16 + q * 4;
                const long long roff =
                    (long long)(gm0 >> wt_shift) * sbT + (gm0 & ((1 << wt_shift) - 1));
                #pragma unroll
                for (int fn = 0; fn < FN; fn++) {
                    const int gn = n0 + wn + fn * 16 + c;
                    const long long a0 = (long long)gn * ldct + roff;
                    u16x4 o;
                    if (add2) {
                        const u16x4 av = *(const u16x4*)&add2[a0];
                        #pragma unroll
                        for (int r = 0; r < 4; r++)
                            o[r] = f2bf(alpha * acc[fm][fn][r] + beta2 * bf2f(av[r]));
                    } else {
                        #pragma unroll
                        for (int r = 0; r < 4; r++)
                            o[r] = f2bf(alpha * acc[fm][fn][r]);
                    }
                    *(u16x4*)&C[a0] = o;
                }
            }
        }
    } else if (atomicf) {
        if constexpr (std::is_same<TC, float>::value) {
            #pragma unroll
            for (int fm = 0; fm < FM; fm++) {
                #pragma unroll
                for (int reg = 0; reg < 4; reg++) {
                    const int gm = m0 + wm + fm * 16 + q * 4 + reg;
                    #pragma unroll
                    for (int fn = 0; fn < FN; fn++) {
                        const int gn = n0 + wn + fn * 16 + c;
                        float v = alpha * acc[fm][fn][reg];
                        if (bias && zh == 0) v += bias[gn];
                        atomicAdd(&C[(size_t)gm * ldc + gn], v);
                    }
                }
            }
        }
    } else {
        #pragma unroll
        for (int fm = 0; fm < FM; fm++) {
            #pragma unroll
            for (int reg = 0; reg < 4; reg++) {
                const int gm = m0 + wm + fm * 16 + q * 4 + reg;
                #pragma unroll
                for (int fn = 0; fn < FN; fn++) {
                    const int gn = n0 + wn + fn * 16 + c;
                    float v = alpha * acc[fm][fn][reg];
                    if (bias) v += bias[gn];
                    if (act == 1) v = 0.5f * v * (1.0f + erff(v * 0.7071067811865475f));
                    if (res)  v += res[(size_t)(gm >> res_shift) * ldres + gn];
                    if constexpr (std::is_same<TC, u16>::value)
                        C[(size_t)gm * ldc + gn] = f2bf(v);
                    else
                        C[(size_t)gm * ldc + gn] = v;
                }
            }
        }
    }
}

// ---------------------------------------------------------------------------
// Fused multi-segment fp32 -> bf16 convert. One dispatch for all weights.
// ---------------------------------------------------------------------------
#define NSEG 14
struct CvtArgs {
    const float* src[NSEG];
    u16*         dst[NSEG];
    int          beg[NSEG + 1];
    int          n4[NSEG];
};

__global__ __launch_bounds__(256)
void k_cvtm(CvtArgs a)
{
    const int blk = blockIdx.x;
    int s = 0;
    #pragma unroll
    for (int i = 1; i < NSEG; i++) if (blk >= a.beg[i]) s = i;
    const int i4 = (blk - a.beg[s]) * 256 + threadIdx.x;
    if (i4 >= a.n4[s]) return;
    const float4 v = *(const float4*)(a.src[s] + (size_t)i4 * 4);
    u16x4 u = { f2bf(v.x), f2bf(v.y), f2bf(v.z), f2bf(v.w) };
    *(u16x4*)(a.dst[s] + (size_t)i4 * 4) = u;
}

// ---------------------------------------------------------------------------
// LayerNorm (512): fp32 in, bf16 out. One wave per row, 4 rows/block.
// ---------------------------------------------------------------------------
__global__ __launch_bounds__(256)
void k_ln(const float* __restrict__ X, u16* __restrict__ Y,
          const float* __restrict__ g, const float* __restrict__ b)
{
    const int row  = blockIdx.x * 4 + threadIdx.y;
    const int lane = threadIdx.x;
    const float* x = X + (size_t)row * DD;
    float v[8];
    float s = 0.0f;
    #pragma unroll
    for (int i = 0; i < 8; i++) { v[i] = x[lane + i * 64]; s += v[i]; }
    #pragma unroll
    for (int off = 32; off; off >>= 1) s += __shfl_xor(s, off, 64);
    const float m = s * (1.0f / 512.0f);
    float qq = 0.0f;
    #pragma unroll
    for (int i = 0; i < 8; i++) { const float d = v[i] - m; qq += d * d; }
    #pragma unroll
    for (int off = 32; off; off >>= 1) qq += __shfl_xor(qq, off, 64);
    const float r = rsqrtf(qq * (1.0f / 512.0f) + 1e-5f);
    u16* y = Y + (size_t)row * DD;
    #pragma unroll
    for (int i = 0; i < 8; i++) {
        const int c = lane + i * 64;
        y[c] = f2bf((v[i] - m) * r * g[c] + b[c]);
    }
}

// ---------------------------------------------------------------------------
// Row softmax on bf16 scores, in place. One wave per row, 4 rows/block.
// ---------------------------------------------------------------------------
template<int COLS>
__global__ __launch_bounds__(256)
void k_softmax(u16* __restrict__ S, const float* __restrict__ mask, int rows_per_b)
{
    const int row  = blockIdx.x * 4 + threadIdx.y;
    const int lane = threadIdx.x;
    u16* p = S + (size_t)row * COLS;
    const float* mrow = mask ? (mask + (size_t)(row / rows_per_b) * COLS) : nullptr;
    constexpr int NP = COLS / 64;
    float v[NP];
    float mx = -3.402823466e38f;
    #pragma unroll
    for (int i = 0; i < NP; i++) {
        const int c = lane + i * 64;
        float x = bf2f(p[c]);
        if (mrow && mrow[c] == 0.0f) x = -3.402823466e38f;
        v[i] = x;
        mx = fmaxf(mx, x);
    }
    #pragma unroll
    for (int off = 32; off; off >>= 1) mx = fmaxf(mx, __shfl_xor(mx, off, 64));
    float s = 0.0f;
    #pragma unroll
    for (int i = 0; i < NP; i++) { v[i] = expf(v[i] - mx); s += v[i]; }
    #pragma unroll
    for (int off = 32; off; off >>= 1) s += __shfl_xor(s, off, 64);
    const float inv = 1.0f / s;
    #pragma unroll
    for (int i = 0; i < NP; i++) p[lane + i * 64] = f2bf(v[i] * inv);
}

// ---------------------------------------------------------------------------
__global__ void k_emb(const int* __restrict__ t, float* __restrict__ emb)
{
    const int idx = blockIdx.x * 256 + threadIdx.x;
    if (idx >= BB * DD) return;
    const int b = idx / DD, c = idx % DD;
    const int j = (c < 256) ? c : (c - 256);
    const float freq = expf((float)j * (-9.210340371976184f / 255.0f));
    const float arg = (float)t[b] * freq;
    emb[idx] = (c < 256) ? sinf(arg) : cosf(arg);
}

// Wave-per-output dense for the tiny time-embed path. act: 0 none, 2 silu
__global__ __launch_bounds__(256)
void k_wlin(const float* __restrict__ in, int K,
            const float* __restrict__ W, const float* __restrict__ bias,
            float* __restrict__ out, int N, int act)
{
    const int gw   = blockIdx.x * 4 + (threadIdx.x >> 6);
    const int lane = threadIdx.x & 63;
    const int b = gw / N, n = gw % N;
    const float* x = in + (size_t)b * K;
    const float* w = W + (size_t)n * K;
    float s = 0.0f;
    for (int k = lane; k < K; k += 64) s += x[k] * w[k];
    #pragma unroll
    for (int off = 32; off; off >>= 1) s += __shfl_xor(s, off, 64);
    if (lane == 0) {
        s += bias[n];
        if (act == 2) s = s / (1.0f + expf(-s));
        out[gw] = s;
    }
}

// ---------------------------------------------------------------------------

extern "C" void kernel_launch(void* const* d_in, const int* in_sizes, int n_in,
                              void* d_out, int out_size, void* d_ws, size_t ws_size,
                              hipStream_t stream)
{
    const float* x_t   = (const float*)d_in[0];
    const int*   tarr  = (const int*)  d_in[1];
    const float* cond  = (const float*)d_in[2];
    const float* cmask = (const float*)d_in[3];
    const float* sa_qw = (const float*)d_in[4];
    const float* sa_kw = (const float*)d_in[5];
    const float* sa_vw = (const float*)d_in[6];
    const float* sa_ow = (const float*)d_in[7];
    const float* sa_ob = (const float*)d_in[8];
    const float* ca_qw = (const float*)d_in[9];
    const float* ca_kw = (const float*)d_in[10];
    const float* ca_vw = (const float*)d_in[11];
    const float* ca_ow = (const float*)d_in[12];
    const float* ca_ob = (const float*)d_in[13];
    const float* f1w   = (const float*)d_in[14];
    const float* f1b   = (const float*)d_in[15];
    const float* f2w   = (const float*)d_in[16];
    const float* f2b   = (const float*)d_in[17];
    const float* n1g   = (const float*)d_in[18];
    const float* n1b   = (const float*)d_in[19];
    const float* n2g   = (const float*)d_in[20];
    const float* n2b   = (const float*)d_in[21];
    const float* n3g   = (const float*)d_in[22];
    const float* n3b   = (const float*)d_in[23];
    const float* tm1w  = (const float*)d_in[24];
    const float* tm1b  = (const float*)d_in[25];
    const float* tm2w  = (const float*)d_in[26];
    const float* tm2b  = (const float*)d_in[27];
    const float* ttw   = (const float*)d_in[28];
    const float* ttb   = (const float*)d_in[29];
    const float* pinw  = (const float*)d_in[30];
    const float* pinb  = (const float*)d_in[31];
    const float* poutw = (const float*)d_in[32];
    const float* poutb = (const float*)d_in[33];
    const float* fng   = (const float*)d_in[34];
    const float* fnb   = (const float*)d_in[35];

    const int M = BB * LQQ; // 2048
    const size_t MB = 1048576;

    char* w8 = (char*)d_ws;
    float* h   = (float*)(w8);                      // [2048,512] fp32  4 MB
    u16*  xn  = (u16*)(w8 +  4 * MB);               // 2 MB
    u16*  qb  = (u16*)(w8 +  6 * MB);               // 2 MB
    u16*  kb  = (u16*)(w8 +  8 * MB);               // 2 MB
    u16*  vbT = (u16*)(w8 + 10 * MB);               // [B,H,64,512] 2 MB
    u16*  ubT = (u16*)(w8 + 12 * MB);               // [B,H,64,512] 2 MB
    u16*  ob  = (u16*)(w8 + 14 * MB);               // 2 MB
    u16*  S   = (u16*)(w8 + 16 * MB);               // [B,H,512,512] bf16 16 MB
    u16*  a1  = S;                                  // FFN hidden aliases S (8 MB)
    u16*  vcT = (u16*)(w8 + 32 * MB);               // [B,H,64,128] 0.5 MB
    float* emb = (float*)(w8 + 33 * MB);
    float* h1t = emb + BB * DD;
    float* te  = h1t + BB * DFFN;
    float* ttv = te  + BB * DD;
    // bf16 weight/input copies
    u16* wq  = (u16*)(w8 + 34 * MB);                // 3 MB each (NL*D*D)
    u16* wk  = (u16*)(w8 + 37 * MB);
    u16* wv  = (u16*)(w8 + 40 * MB);
    u16* wo  = (u16*)(w8 + 43 * MB);
    u16* cwq = (u16*)(w8 + 46 * MB);
    u16* cwk = (u16*)(w8 + 49 * MB);
    u16* cwv = (u16*)(w8 + 52 * MB);
    u16* cwo = (u16*)(w8 + 55 * MB);
    u16* w1  = (u16*)(w8 + 58 * MB);                // 12 MB (NL*DFF*D)
    u16* w2  = (u16*)(w8 + 70 * MB);                // 12 MB
    u16* wpi = (u16*)(w8 + 82 * MB);                // 256 KB
    u16* wpo = (u16*)(w8 + 82 * MB + 262144);       // 256 KB
    u16* xtb = (u16*)(w8 + 83 * MB);                // 1 MB (x_t bf16)
    u16* cdb = (u16*)(w8 + 84 * MB);                // 512 KB (cond bf16)

    const dim3 T256(256);
    const dim3 LN_B(64, 4);
    const long long ZA  = (long long)LQQ * DD;      // 262144
    const long long ZS  = (long long)LQQ * LQQ;     // 262144
    const long long ZC  = (long long)LQQ * LCC;     // 65536
    const long long ZVT = (long long)HH * HD * LQQ; // 262144
    const long long ZVH = (long long)HD * LQQ;      // 32768
    const long long ZWT = (long long)HH * HD * LCC; // 65536
    const long long ZKB = (long long)LCC * DD;      // 65536 (cross kb per-b)

    // ---- one fused bf16 conversion dispatch for all weights/inputs ----
    {
        const int NW4 = NLAYER * DD * DD / 4;     // 393216
        const int NF4 = NLAYER * DFFN * DD / 4;   // 1572864
        CvtArgs a;
        const float* srcs[NSEG] = { sa_qw, sa_kw, sa_vw, sa_ow, ca_qw, ca_kw, ca_vw, ca_ow,
                                    f1w, f2w, pinw, poutw, x_t, cond };
        u16* dsts[NSEG] = { wq, wk, wv, wo, cwq, cwk, cwv, cwo,
                            w1, w2, wpi, wpo, xtb, cdb };
        const int n4s[NSEG] = { NW4, NW4, NW4, NW4, NW4, NW4, NW4, NW4,
                                NF4, NF4, DD * LATD / 4, LATD * DD / 4,
                                M * LATD / 4, BB * LCC * DD / 4 };
        int acc = 0;
        for (int i = 0; i < NSEG; i++) {
            a.src[i] = srcs[i]; a.dst[i] = dsts[i]; a.n4[i] = n4s[i];
            a.beg[i] = acc; acc += (n4s[i] + 255) / 256;
        }
        a.beg[NSEG] = acc;
        k_cvtm<<<acc, T256, 0, stream>>>(a);
    }

    // ---- time embedding path ----
    k_emb<<<(BB * DD + 255) / 256, 256, 0, stream>>>(tarr, emb);
    k_wlin<<<(BB * DFFN) / 4, T256, 0, stream>>>(emb, DD, tm1w, tm1b, h1t, DFFN, 2);
    k_wlin<<<(BB * DD) / 4,   T256, 0, stream>>>(h1t, DFFN, tm2w, tm2b, te, DD, 0);
    k_wlin<<<(BB * DD) / 4,   T256, 0, stream>>>(te, DD, ttw, ttb, ttv, DD, 0);

    // ---- input projection: h = x_t @ pinw.T + pinb + ttv[b]  (res_shift=9) ----
    k_g<32, 64, float, false><<<dim3(DD / 64, M / 32, 1), T256, 0, stream>>>(
        xtb, 0, 0, LATD, wpi, nullptr, nullptr, 0, 0, LATD,
        h, nullptr, nullptr, 0, 0, DD,
        LATD, 1, 1.0f, pinb, ttv, DD, 9, 0.0f, nullptr, 0, 0, 0, 0, 0, 0, 0, 0);

    for (int L = 0; L < NLAYER; L++) {
        const size_t LW = (size_t)L * DD * DD;

        // ======== self-attention with QGFD ========
        k_ln<<<M / 4, LN_B, 0, stream>>>(h, xn, n1g + (size_t)L * DD, n1b + (size_t)L * DD);

        // fused QKV (z: 0=q, 1=k, 2=v transposed write) — 768 blocks
        k_g<64, 64, u16, true><<<dim3(DD / 64, M / 64, 3), T256, 0, stream>>>(
            xn, 0, 0, DD, wq + LW, wk + LW, wv + LW, 0, 0, DD,
            qb, kb, vbT, 0, 0, DD,
            DD, 1, 1.0f, nullptr, nullptr, 0, 0, 0.0f, nullptr, 0, 0, 0, 0,
            /*wt_mask=*/4, /*wt_shift=*/9, /*sbT=*/ZVT, /*ldct=*/LQQ);

        // S = 0.125 * q @ k^T   (bf16) — 2048 blocks
        k_g<64, 64, u16, false><<<dim3(LQQ / 64, LQQ / 64, BB * HH), T256, 0, stream>>>(
            qb, ZA, 64, DD, kb, nullptr, nullptr, ZA, 64, DD,
            S, nullptr, nullptr, (long long)HH * ZS, ZS, LQQ,
            HD, HH, 0.125f, nullptr, nullptr, 0, 0, 0.0f, nullptr, 0, 0, 0, 0, 0, 0, 0, 0);
        k_softmax<LQQ><<<(BB * HH * LQQ) / 4, LN_B, 0, stream>>>(S, nullptr, 1);

        // QGFD: ubT = (0.5*(P@v) + 0.5*v)^T — 512 blocks
        k_g<32, 64, u16, false><<<dim3(1, LQQ / 32, BB * HH), T256, 0, stream>>>(
            S, (long long)HH * ZS, ZS, LQQ, vbT, nullptr, nullptr, ZVT, ZVH, LQQ,
            ubT, nullptr, nullptr, ZVT, ZVH, LQQ,
            LQQ, HH, 0.5f, nullptr, nullptr, 0, 0, 0.5f, vbT, ZVT, ZVH, 0, 0,
            /*wt=*/1, /*shift=*/30, /*sbT=*/0, /*ldct=*/LQQ);
        // ob = P @ ub — 512 blocks
        k_g<32, 64, u16, false><<<dim3(1, LQQ / 32, BB * HH), T256, 0, stream>>>(
            S, (long long)HH * ZS, ZS, LQQ, ubT, nullptr, nullptr, ZVT, ZVH, LQQ,
            ob, nullptr, nullptr, ZA, 64, DD,
            LQQ, HH, 1.0f, nullptr, nullptr, 0, 0, 0.0f, nullptr, 0, 0, 0, 0, 0, 0, 0, 0);

        // h += ob @ ow.T + obias — split-K x2, atomic, 1024 blocks
        k_g<32, 64, float, false><<<dim3(DD / 64, M / 32, 2), T256, 0, stream>>>(
            ob, 0, 256, DD, wo + LW, nullptr, nullptr, 0, 256, DD,
            h, nullptr, nullptr, 0, 0, DD,
            256, 2, 1.0f, sa_ob + (size_t)L * DD, nullptr, 0, 0, 0.0f, nullptr, 0, 0,
            0, /*atomic=*/1, 0, 0, 0, 0);

        // ======== cross-attention ========
        k_ln<<<M / 4, LN_B, 0, stream>>>(h, xn, n2g + (size_t)L * DD, n2b + (size_t)L * DD);

        // cross q — 512 blocks
        k_g<32, 64, u16, false><<<dim3(DD / 64, M / 32, 1), T256, 0, stream>>>(
            xn, 0, 0, DD, cwq + LW, nullptr, nullptr, 0, 0, DD,
            qb, nullptr, nullptr, 0, 0, DD,
            DD, 1, 1.0f, nullptr, nullptr, 0, 0, 0.0f, nullptr, 0, 0, 0, 0, 0, 0, 0, 0);

        // fused cross K/V (z: 0=k, 1=v transposed) — 256 blocks
        k_g<32, 64, u16, true><<<dim3(DD / 64, (BB * LCC) / 32, 2), T256, 0, stream>>>(
            cdb, 0, 0, DD, cwk + LW, cwv + LW, nullptr, 0, 0, DD,
            kb, vcT, nullptr, 0, 0, DD,
            DD, 1, 1.0f, nullptr, nullptr, 0, 0, 0.0f, nullptr, 0, 0, 0, 0,
            /*wt_mask=*/2, /*wt_shift=*/7, /*sbT=*/ZWT, /*ldct=*/LCC);

        // Sc = 0.125 * q @ kc^T — 512 blocks
        k_g<64, 64, u16, false><<<dim3(LCC / 64, LQQ / 64, BB * HH), T256, 0, stream>>>(
            qb, ZA, 64, DD, kb, nullptr, nullptr, ZKB, 64, DD,
            S, nullptr, nullptr, (long long)HH * ZC, ZC, LCC,
            HD, HH, 0.125f, nullptr, nullptr, 0, 0, 0.0f, nullptr, 0, 0, 0, 0, 0, 0, 0, 0);
        k_softmax<LCC><<<(BB * HH * LQQ) / 4, LN_B, 0, stream>>>(S, cmask, HH * LQQ);

        // ob = Pc @ vc — 512 blocks
        k_g<32, 64, u16, false><<<dim3(1, LQQ / 32, BB * HH), T256, 0, stream>>>(
            S, (long long)HH * ZC, ZC, LCC, vcT, nullptr, nullptr, ZWT, (long long)HD * LCC, LCC,
            ob, nullptr, nullptr, ZA, 64, DD,
            LCC, HH, 1.0f, nullptr, nullptr, 0, 0, 0.0f, nullptr, 0, 0, 0, 0, 0, 0, 0, 0);

        // h += ob @ cow.T + cob — split-K x2, atomic, 1024 blocks
        k_g<32, 64, float, false><<<dim3(DD / 64, M / 32, 2), T256, 0, stream>>>(
            ob, 0, 256, DD, cwo + LW, nullptr, nullptr, 0, 256, DD,
            h, nullptr, nullptr, 0, 0, DD,
            256, 2, 1.0f, ca_ob + (size_t)L * DD, nullptr, 0, 0, 0.0f, nullptr, 0, 0,
            0, /*atomic=*/1, 0, 0, 0, 0);

        // ======== FFN ========
        k_ln<<<M / 4, LN_B, 0, stream>>>(h, xn, n3g + (size_t)L * DD, n3b + (size_t)L * DD);

        // a1 = gelu(xn @ f1w.T + f1b) — 1024 blocks
        k_g<64, 64, u16, false><<<dim3(DFFN / 64, M / 64, 1), T256, 0, stream>>>(
            xn, 0, 0, DD, w1 + (size_t)L * DFFN * DD, nullptr, nullptr, 0, 0, DD,
            a1, nullptr, nullptr, 0, 0, DFFN,
            DD, 1, 1.0f, f1b + (size_t)L * DFFN, nullptr, 0, 0, 0.0f, nullptr, 0, 0,
            /*act=*/1, 0, 0, 0, 0, 0);
        // h += a1 @ f2w.T + f2b — split-K x4, atomic, 2048 blocks
        k_g<32, 64, float, false><<<dim3(DD / 64, M / 32, 4), T256, 0, stream>>>(
            a1, 0, 512, DFFN, w2 + (size_t)L * DD * DFFN, nullptr, nullptr, 0, 512, DFFN,
            h, nullptr, nullptr, 0, 0, DD,
            512, 4, 1.0f, f2b + (size_t)L * DD, nullptr, 0, 0, 0.0f, nullptr, 0, 0,
            0, /*atomic=*/1, 0, 0, 0, 0);
    }

    // ---- final LN + output projection (fp32 out to d_out) — 512 blocks ----
    k_ln<<<M / 4, LN_B, 0, stream>>>(h, xn, fng, fnb);
    k_g<32, 32, float, false><<<dim3(LATD / 32, M / 32, 1), T256, 0, stream>>>(
        xn, 0, 0, DD, wpo, nullptr, nullptr, 0, 0, DD,
        (float*)d_out, nullptr, nullptr, 0, 0, LATD,
        DD, 1, 1.0f, poutb, nullptr, 0, 0, 0.0f, nullptr, 0, 0, 0, 0, 0, 0, 0, 0);
}

// Round 8
// 1787.825 us; speedup vs baseline: 1.1586x; 1.1586x over previous
//
#include <hip/hip_runtime.h>
#include <hip/hip_bf16.h>
#include <type_traits>

#define DD    512
#define HH    8
#define HD    64
#define NLAYER 6
#define DFFN  2048
#define LATD  256
#define BB    4
#define LQQ   512
#define LCC   128

typedef unsigned short u16;
typedef __attribute__((ext_vector_type(8))) short bf16x8;
typedef __attribute__((ext_vector_type(4))) float f32x4;
typedef __attribute__((ext_vector_type(4))) unsigned short u16x4;

__device__ __forceinline__ u16 f2bf(float f) {
    __hip_bfloat16 h = __float2bfloat16(f);
    return __builtin_bit_cast(u16, h);
}
__device__ __forceinline__ float bf2f(u16 u) {
    return __uint_as_float(((unsigned int)u) << 16);
}

// ---------------------------------------------------------------------------
// MFMA bf16 GEMM, all operands bf16, B is [N][K] row-major.
// BK=64, LDS double-buffer + 2-slot register pipeline (round-7, verified).
// MULTI: blockIdx.z selects (B,C) from up to 3; else z=zb*Hdim+zh batches.
// wt: transposed epilogue C[gn*ldct + (gm>>wt_shift)*sbT + (gm&mask)].
// normal: v=alpha*acc + bias[n]; act==1 exact gelu; += res[(gm>>rs)*ldres+gn].
// ---------------------------------------------------------------------------
template<int BM, int BN, typename TC, bool MULTI>
__global__ __launch_bounds__(256)
void k_g(const u16* __restrict__ A, long long sAb, long long sAh, int lda,
         const u16* __restrict__ B1, const u16* __restrict__ B2_, const u16* __restrict__ B3_,
         long long sBb, long long sBh, int ldb,
         TC* __restrict__ C1, TC* __restrict__ C2_, TC* __restrict__ C3_,
         long long sCb, long long sCh, int ldc,
         int K, int Hdim, float alpha,
         const float* __restrict__ bias,
         const float* __restrict__ res, int ldres, int res_shift,
         float beta2, const u16* __restrict__ add2, long long s2b, long long s2h,
         int act, int wt_mask, int wt_shift, long long sbT, int ldct)
{
    constexpr int SK = 72;
    constexpr int FM = BM / 32, FN = BN / 32;
    constexpr int PA = BM / 32, PB = BN / 32;

    const int z = blockIdx.z;
    const u16* Bm;
    TC* C;
    int wt;
    if constexpr (MULTI) {
        Bm = (z == 0) ? B1 : ((z == 1) ? B2_ : B3_);
        C  = (z == 0) ? C1 : ((z == 1) ? C2_ : C3_);
        wt = (wt_mask >> z) & 1;
    } else {
        const int zb = z / Hdim, zh = z % Hdim;
        A += (size_t)(zb * sAb + zh * sAh);
        Bm = B1 + (size_t)(zb * sBb + zh * sBh);
        C  = C1 + (size_t)(zb * sCb + zh * sCh);
        if (add2) add2 += (size_t)(zb * s2b + zh * s2h);
        wt = wt_mask & 1;
    }

    __shared__ u16 Asm[2][BM * SK];
    __shared__ u16 Bsm[2][BN * SK];

    const int t    = threadIdx.x;
    const int wid  = t >> 6, lane = t & 63;
    const int q    = lane >> 4, c = lane & 15;
    const int wm   = (wid >> 1) * (BM / 2), wn = (wid & 1) * (BN / 2);
    const int m0   = blockIdx.y * BM, n0 = blockIdx.x * BN;

    f32x4 acc[FM][FN];
    #pragma unroll
    for (int i = 0; i < FM; i++)
        #pragma unroll
        for (int j = 0; j < FN; j++) acc[i][j] = (f32x4){0.f, 0.f, 0.f, 0.f};

    uint4 ra[2][PA], rb[2][PB];
    const int NI = K >> 6;

    auto loadg = [&](int slot, int kt) {
        #pragma unroll
        for (int p = 0; p < PA; p++) {
            const int idx = p * 256 + t, r = idx >> 3, kg = (idx & 7) << 3;
            ra[slot][p] = *(const uint4*)(A + (size_t)(m0 + r) * lda + kt + kg);
        }
        #pragma unroll
        for (int p = 0; p < PB; p++) {
            const int idx = p * 256 + t, r = idx >> 3, kg = (idx & 7) << 3;
            rb[slot][p] = *(const uint4*)(Bm + (size_t)(n0 + r) * ldb + kt + kg);
        }
    };
    auto store = [&](int buf, int slot) {
        #pragma unroll
        for (int p = 0; p < PA; p++) {
            const int idx = p * 256 + t, r = idx >> 3, kg = (idx & 7) << 3;
            *(uint4*)&Asm[buf][r * SK + kg] = ra[slot][p];
        }
        #pragma unroll
        for (int p = 0; p < PB; p++) {
            const int idx = p * 256 + t, r = idx >> 3, kg = (idx & 7) << 3;
            *(uint4*)&Bsm[buf][r * SK + kg] = rb[slot][p];
        }
    };

    loadg(0, 0);
    if (NI > 1) loadg(1, 64);
    store(0, 0);

    for (int it = 0; it < NI; it++) {
        __syncthreads();
        const int cur = it & 1, nxt = cur ^ 1;
        if (it + 1 < NI) store(nxt, nxt);
        if (it + 2 < NI) loadg(cur, (it + 2) << 6);
        #pragma unroll
        for (int s = 0; s < 2; s++) {
            bf16x8 af[FM], bfv[FN];
            #pragma unroll
            for (int fm = 0; fm < FM; fm++)
                af[fm] = *(const bf16x8*)&Asm[cur][(wm + fm * 16 + c) * SK + s * 32 + q * 8];
            #pragma unroll
            for (int fn = 0; fn < FN; fn++)
                bfv[fn] = *(const bf16x8*)&Bsm[cur][(wn + fn * 16 + c) * SK + s * 32 + q * 8];
            #pragma unroll
            for (int fm = 0; fm < FM; fm++)
                #pragma unroll
                for (int fn = 0; fn < FN; fn++)
                    acc[fm][fn] = __builtin_amdgcn_mfma_f32_16x16x32_bf16(
                        af[fm], bfv[fn], acc[fm][fn], 0, 0, 0);
        }
    }

    if (wt) {
        if constexpr (std::is_same<TC, u16>::value) {
            #pragma unroll
            for (int fm = 0; fm < FM; fm++) {
                const int gm0 = m0 + wm + fm * 16 + q * 4;
                const long long roff =
                    (long long)(gm0 >> wt_shift) * sbT + (gm0 & ((1 << wt_shift) - 1));
                #pragma unroll
                for (int fn = 0; fn < FN; fn++) {
                    const int gn = n0 + wn + fn * 16 + c;
                    const long long a0 = (long long)gn * ldct + roff;
                    u16x4 o;
                    if (add2) {
                        const u16x4 av = *(const u16x4*)&add2[a0];
                        #pragma unroll
                        for (int r = 0; r < 4; r++)
                            o[r] = f2bf(alpha * acc[fm][fn][r] + beta2 * bf2f(av[r]));
                    } else {
                        #pragma unroll
                        for (int r = 0; r < 4; r++)
                            o[r] = f2bf(alpha * acc[fm][fn][r]);
                    }
                    *(u16x4*)&C[a0] = o;
                }
            }
        }
    } else {
        #pragma unroll
        for (int fm = 0; fm < FM; fm++) {
            #pragma unroll
            for (int reg = 0; reg < 4; reg++) {
                const int gm = m0 + wm + fm * 16 + q * 4 + reg;
                #pragma unroll
                for (int fn = 0; fn < FN; fn++) {
                    const int gn = n0 + wn + fn * 16 + c;
                    float v = alpha * acc[fm][fn][reg];
                    if (bias) v += bias[gn];
                    if (act == 1) v = 0.5f * v * (1.0f + erff(v * 0.7071067811865475f));
                    if (res)  v += res[(size_t)(gm >> res_shift) * ldres + gn];
                    if constexpr (std::is_same<TC, u16>::value)
                        C[(size_t)gm * ldc + gn] = f2bf(v);
                    else
                        C[(size_t)gm * ldc + gn] = v;
                }
            }
        }
    }
}

// ---------------------------------------------------------------------------
// Fused attention: one block = 64 q-rows x one (b,h) head.
// Phase 1: S = q @ k^T (LDS-staged K chunks of 128), row softmax in registers
//          (alpha pre-scale; optional key mask). SELF also writes P (bf16).
// Phase 2: u = P @ v via LDS round-trip per 128-col chunk.
//   SELF : uout = ubT[b,h,64,512] = (0.5*u + 0.5*v)^T
//   CROSS: uout = ob rows [B*LQ, DD] head slice (no blend, no P write)
// Wave layout: 4 waves x 16 rows; per-row data on 16-lane groups (q=lane>>4).
// ---------------------------------------------------------------------------
template<bool SELF>
__global__ __launch_bounds__(256)
void k_attn(const u16* __restrict__ qb, const u16* __restrict__ kb,
            const u16* __restrict__ vT, u16* __restrict__ P,
            u16* __restrict__ uout, const float* __restrict__ mask,
            float alpha)
{
    constexpr int LK  = SELF ? LQQ : LCC;
    constexpr int NCT = LK / 128;
    constexpr int NJ  = LK / 16;
    constexpr int SM1 = 64 * 72 * 2 + (SELF ? 2 : 1) * 128 * 72 * 2;
    constexpr int SM2 = 2 * 64 * 136 * 2;
    constexpr int SMEM = SM1 > SM2 ? SM1 : SM2;
    __shared__ char smem[SMEM];
    u16* Qs = (u16*)smem;
    u16* Ks = (u16*)(smem + 64 * 72 * 2);
    u16* Ps = (u16*)smem;
    u16* Vs = (u16*)(smem + 64 * 136 * 2);

    const int z = blockIdx.z, b = z >> 3, hh = z & 7;
    const int m0 = blockIdx.y * 64;
    const int t = threadIdx.x, w = t >> 6, lane = t & 63;
    const int q = lane >> 4, c = lane & 15;

    const u16* qbase = qb + ((size_t)(b * LQQ + m0)) * DD + hh * HD;
    const u16* kbase = kb + ((size_t)b * LK) * DD + hh * HD;
    const u16* vbase = vT + (size_t)z * HD * LK;

    // ---- stage Q (64 x 64) ----
    #pragma unroll
    for (int p = 0; p < 2; p++) {
        const int idx = p * 256 + t, r = idx >> 3, kg = (idx & 7) << 3;
        *(uint4*)&Qs[r * 72 + kg] = *(const uint4*)(qbase + (size_t)r * DD + kg);
    }

    f32x4 acc[NJ];
    #pragma unroll
    for (int j = 0; j < NJ; j++) acc[j] = (f32x4){0.f, 0.f, 0.f, 0.f};

    auto stageK = [&](u16* dst, int ct) {
        #pragma unroll
        for (int p = 0; p < 4; p++) {
            const int idx = p * 256 + t, r = idx >> 3, kg = (idx & 7) << 3;
            *(uint4*)&dst[r * 72 + kg] =
                *(const uint4*)(kbase + (size_t)(ct * 128 + r) * DD + kg);
        }
    };

    stageK(Ks, 0);
    __syncthreads();
    #pragma unroll
    for (int ct = 0; ct < NCT; ct++) {
        u16* cur = Ks + (SELF ? (ct & 1) * (128 * 72) : 0);
        if (SELF && ct + 1 < NCT)
            stageK(Ks + ((ct + 1) & 1) * (128 * 72), ct + 1);
        #pragma unroll
        for (int s = 0; s < 2; s++) {
            const bf16x8 af = *(const bf16x8*)&Qs[(w * 16 + c) * 72 + s * 32 + q * 8];
            #pragma unroll
            for (int fn = 0; fn < 8; fn++) {
                const bf16x8 bv = *(const bf16x8*)&cur[(fn * 16 + c) * 72 + s * 32 + q * 8];
                acc[ct * 8 + fn] = __builtin_amdgcn_mfma_f32_16x16x32_bf16(
                    af, bv, acc[ct * 8 + fn], 0, 0, 0);
            }
        }
        if (SELF && ct + 1 < NCT) __syncthreads();
    }

    // ---- row softmax (rows q*4+reg per wave; cols j*16+c) ----
    bool msk[NJ];
    #pragma unroll
    for (int j = 0; j < NJ; j++) {
        msk[j] = false;
        if (!SELF && mask) msk[j] = (mask[b * LCC + j * 16 + c] == 0.0f);
    }
    float mx[4] = {-3.402823466e38f, -3.402823466e38f, -3.402823466e38f, -3.402823466e38f};
    #pragma unroll
    for (int j = 0; j < NJ; j++)
        #pragma unroll
        for (int r = 0; r < 4; r++) {
            float x = alpha * acc[j][r];
            if (msk[j]) x = -3.402823466e38f;
            acc[j][r] = x;
            mx[r] = fmaxf(mx[r], x);
        }
    #pragma unroll
    for (int r = 0; r < 4; r++)
        #pragma unroll
        for (int m = 8; m; m >>= 1) mx[r] = fmaxf(mx[r], __shfl_xor(mx[r], m, 64));
    float sum[4] = {0.f, 0.f, 0.f, 0.f};
    #pragma unroll
    for (int j = 0; j < NJ; j++)
        #pragma unroll
        for (int r = 0; r < 4; r++) {
            const float e = expf(acc[j][r] - mx[r]);
            acc[j][r] = e;
            sum[r] += e;
        }
    #pragma unroll
    for (int r = 0; r < 4; r++)
        #pragma unroll
        for (int m = 8; m; m >>= 1) sum[r] += __shfl_xor(sum[r], m, 64);
    #pragma unroll
    for (int r = 0; r < 4; r++) sum[r] = 1.0f / sum[r];
    #pragma unroll
    for (int j = 0; j < NJ; j++)
        #pragma unroll
        for (int r = 0; r < 4; r++) acc[j][r] *= sum[r];

    // ---- SELF: write P (needed by second propagation GEMM) ----
    if (SELF) {
        #pragma unroll
        for (int j = 0; j < NJ; j++)
            #pragma unroll
            for (int r = 0; r < 4; r++)
                P[((size_t)z * LQQ + m0 + w * 16 + q * 4 + r) * LQQ + j * 16 + c] =
                    f2bf(acc[j][r]);
    }

    // ---- phase 2: u = P @ v ----
    f32x4 ua[4];
    #pragma unroll
    for (int fn = 0; fn < 4; fn++) ua[fn] = (f32x4){0.f, 0.f, 0.f, 0.f};

    __syncthreads();   // phase boundary: Qs/Ks -> Ps/Vs alias
    #pragma unroll
    for (int ct = 0; ct < NCT; ct++) {
        #pragma unroll
        for (int j = 0; j < 8; j++)
            #pragma unroll
            for (int r = 0; r < 4; r++)
                Ps[(w * 16 + q * 4 + r) * 136 + j * 16 + c] = f2bf(acc[ct * 8 + j][r]);
        #pragma unroll
        for (int p = 0; p < 4; p++) {
            const int idx = p * 256 + t, rr = idx >> 4, kg = (idx & 15) << 3;
            *(uint4*)&Vs[rr * 136 + kg] =
                *(const uint4*)(vbase + (size_t)rr * LK + ct * 128 + kg);
        }
        __syncthreads();
        #pragma unroll
        for (int ks = 0; ks < 4; ks++) {
            const bf16x8 af = *(const bf16x8*)&Ps[(w * 16 + c) * 136 + ks * 32 + q * 8];
            #pragma unroll
            for (int fn = 0; fn < 4; fn++) {
                const bf16x8 bv = *(const bf16x8*)&Vs[(fn * 16 + c) * 136 + ks * 32 + q * 8];
                ua[fn] = __builtin_amdgcn_mfma_f32_16x16x32_bf16(af, bv, ua[fn], 0, 0, 0);
            }
        }
        if (ct + 1 < NCT) __syncthreads();
    }

    // ---- epilogue ----
    if (SELF) {
        #pragma unroll
        for (int fn = 0; fn < 4; fn++) {
            const int col = fn * 16 + c;
            const size_t a0 = ((size_t)z * HD + col) * LQQ + m0 + w * 16 + q * 4;
            const u16x4 vv = *(const u16x4*)&vT[a0];
            u16x4 o;
            #pragma unroll
            for (int r = 0; r < 4; r++)
                o[r] = f2bf(0.5f * ua[fn][r] + 0.5f * bf2f(vv[r]));
            *(u16x4*)&uout[a0] = o;
        }
    } else {
        #pragma unroll
        for (int fn = 0; fn < 4; fn++)
            #pragma unroll
            for (int r = 0; r < 4; r++)
                uout[((size_t)b * LQQ + m0 + w * 16 + q * 4 + r) * DD + hh * HD + fn * 16 + c] =
                    f2bf(ua[fn][r]);
    }
}

// ---------------------------------------------------------------------------
#define NSEG 14
struct CvtArgs {
    const float* src[NSEG];
    u16*         dst[NSEG];
    int          beg[NSEG + 1];
    int          n4[NSEG];
};

__global__ __launch_bounds__(256)
void k_cvtm(CvtArgs a)
{
    const int blk = blockIdx.x;
    int s = 0;
    #pragma unroll
    for (int i = 1; i < NSEG; i++) if (blk >= a.beg[i]) s = i;
    const int i4 = (blk - a.beg[s]) * 256 + threadIdx.x;
    if (i4 >= a.n4[s]) return;
    const float4 v = *(const float4*)(a.src[s] + (size_t)i4 * 4);
    u16x4 u = { f2bf(v.x), f2bf(v.y), f2bf(v.z), f2bf(v.w) };
    *(u16x4*)(a.dst[s] + (size_t)i4 * 4) = u;
}

// ---------------------------------------------------------------------------
__global__ __launch_bounds__(256)
void k_ln(const float* __restrict__ X, u16* __restrict__ Y,
          const float* __restrict__ g, const float* __restrict__ b)
{
    const int row  = blockIdx.x * 4 + threadIdx.y;
    const int lane = threadIdx.x;
    const float* x = X + (size_t)row * DD;
    float v[8];
    float s = 0.0f;
    #pragma unroll
    for (int i = 0; i < 8; i++) { v[i] = x[lane + i * 64]; s += v[i]; }
    #pragma unroll
    for (int off = 32; off; off >>= 1) s += __shfl_xor(s, off, 64);
    const float m = s * (1.0f / 512.0f);
    float qq = 0.0f;
    #pragma unroll
    for (int i = 0; i < 8; i++) { const float d = v[i] - m; qq += d * d; }
    #pragma unroll
    for (int off = 32; off; off >>= 1) qq += __shfl_xor(qq, off, 64);
    const float r = rsqrtf(qq * (1.0f / 512.0f) + 1e-5f);
    u16* y = Y + (size_t)row * DD;
    #pragma unroll
    for (int i = 0; i < 8; i++) {
        const int c = lane + i * 64;
        y[c] = f2bf((v[i] - m) * r * g[c] + b[c]);
    }
}

// ---------------------------------------------------------------------------
__global__ void k_emb(const int* __restrict__ t, float* __restrict__ emb)
{
    const int idx = blockIdx.x * 256 + threadIdx.x;
    if (idx >= BB * DD) return;
    const int b = idx / DD, c = idx % DD;
    const int j = (c < 256) ? c : (c - 256);
    const float freq = expf((float)j * (-9.210340371976184f / 255.0f));
    const float arg = (float)t[b] * freq;
    emb[idx] = (c < 256) ? sinf(arg) : cosf(arg);
}

__global__ __launch_bounds__(256)
void k_wlin(const float* __restrict__ in, int K,
            const float* __restrict__ W, const float* __restrict__ bias,
            float* __restrict__ out, int N, int act)
{
    const int gw   = blockIdx.x * 4 + (threadIdx.x >> 6);
    const int lane = threadIdx.x & 63;
    const int b = gw / N, n = gw % N;
    const float* x = in + (size_t)b * K;
    const float* w = W + (size_t)n * K;
    float s = 0.0f;
    for (int k = lane; k < K; k += 64) s += x[k] * w[k];
    #pragma unroll
    for (int off = 32; off; off >>= 1) s += __shfl_xor(s, off, 64);
    if (lane == 0) {
        s += bias[n];
        if (act == 2) s = s / (1.0f + expf(-s));
        out[gw] = s;
    }
}

// ---------------------------------------------------------------------------

extern "C" void kernel_launch(void* const* d_in, const int* in_sizes, int n_in,
                              void* d_out, int out_size, void* d_ws, size_t ws_size,
                              hipStream_t stream)
{
    const float* x_t   = (const float*)d_in[0];
    const int*   tarr  = (const int*)  d_in[1];
    const float* cond  = (const float*)d_in[2];
    const float* cmask = (const float*)d_in[3];
    const float* sa_qw = (const float*)d_in[4];
    const float* sa_kw = (const float*)d_in[5];
    const float* sa_vw = (const float*)d_in[6];
    const float* sa_ow = (const float*)d_in[7];
    const float* sa_ob = (const float*)d_in[8];
    const float* ca_qw = (const float*)d_in[9];
    const float* ca_kw = (const float*)d_in[10];
    const float* ca_vw = (const float*)d_in[11];
    const float* ca_ow = (const float*)d_in[12];
    const float* ca_ob = (const float*)d_in[13];
    const float* f1w   = (const float*)d_in[14];
    const float* f1b   = (const float*)d_in[15];
    const float* f2w   = (const float*)d_in[16];
    const float* f2b   = (const float*)d_in[17];
    const float* n1g   = (const float*)d_in[18];
    const float* n1b   = (const float*)d_in[19];
    const float* n2g   = (const float*)d_in[20];
    const float* n2b   = (const float*)d_in[21];
    const float* n3g   = (const float*)d_in[22];
    const float* n3b   = (const float*)d_in[23];
    const float* tm1w  = (const float*)d_in[24];
    const float* tm1b  = (const float*)d_in[25];
    const float* tm2w  = (const float*)d_in[26];
    const float* tm2b  = (const float*)d_in[27];
    const float* ttw   = (const float*)d_in[28];
    const float* ttb   = (const float*)d_in[29];
    const float* pinw  = (const float*)d_in[30];
    const float* pinb  = (const float*)d_in[31];
    const float* poutw = (const float*)d_in[32];
    const float* poutb = (const float*)d_in[33];
    const float* fng   = (const float*)d_in[34];
    const float* fnb   = (const float*)d_in[35];

    const int M = BB * LQQ; // 2048
    const size_t MB = 1048576;

    char* w8 = (char*)d_ws;
    float* h   = (float*)(w8);                      // [2048,512] fp32  4 MB
    u16*  xn  = (u16*)(w8 +  4 * MB);               // 2 MB
    u16*  qb  = (u16*)(w8 +  6 * MB);               // 2 MB
    u16*  kb  = (u16*)(w8 +  8 * MB);               // 2 MB (self K)
    u16*  vbT = (u16*)(w8 + 10 * MB);               // [B,H,64,512] 2 MB
    u16*  ubT = (u16*)(w8 + 12 * MB);               // [B,H,64,512] 2 MB
    u16*  ob  = (u16*)(w8 + 14 * MB);               // 2 MB
    u16*  P   = (u16*)(w8 + 16 * MB);               // [B,H,512,512] bf16 16 MB
    u16*  a1  = P;                                  // FFN hidden aliases P (8 MB)
    u16*  xtb = (u16*)(w8 + 16 * MB);               // aliases P (dead before attn)
    u16*  cdb = (u16*)(w8 + 17 * MB);               // aliases P (dead before attn)
    u16*  kbc6 = (u16*)(w8 + 32 * MB);              // 6 x [B*LCC, DD] = 3 MB
    u16*  vcT6 = (u16*)(w8 + 35 * MB);              // 6 x [B,H,64,128] = 3 MB
    float* emb = (float*)(w8 + 38 * MB);
    float* h1t = emb + BB * DD;
    float* te  = h1t + BB * DFFN;
    float* ttv = te  + BB * DD;
    u16* wq  = (u16*)(w8 + 39 * MB);
    u16* wk  = (u16*)(w8 + 42 * MB);
    u16* wv  = (u16*)(w8 + 45 * MB);
    u16* wo  = (u16*)(w8 + 48 * MB);
    u16* cwq = (u16*)(w8 + 51 * MB);
    u16* cwk = (u16*)(w8 + 54 * MB);
    u16* cwv = (u16*)(w8 + 57 * MB);
    u16* cwo = (u16*)(w8 + 60 * MB);
    u16* w1  = (u16*)(w8 + 63 * MB);                // 12 MB
    u16* w2  = (u16*)(w8 + 75 * MB);                // 12 MB
    u16* wpi = (u16*)(w8 + 87 * MB);                // 256 KB
    u16* wpo = (u16*)(w8 + 87 * MB + 262144);       // 256 KB

    const dim3 T256(256);
    const dim3 LN_B(64, 4);
    const long long ZA  = (long long)LQQ * DD;      // 262144
    const long long ZS  = (long long)LQQ * LQQ;     // 262144
    const long long ZVT = (long long)HH * HD * LQQ; // 262144
    const long long ZVH = (long long)HD * LQQ;      // 32768
    const long long ZWT = (long long)HH * HD * LCC; // 65536
    const long long ZKB = (long long)LCC * DD;      // 65536

    // ---- one fused bf16 conversion dispatch ----
    {
        const int NW4 = NLAYER * DD * DD / 4;
        const int NF4 = NLAYER * DFFN * DD / 4;
        CvtArgs a;
        const float* srcs[NSEG] = { sa_qw, sa_kw, sa_vw, sa_ow, ca_qw, ca_kw, ca_vw, ca_ow,
                                    f1w, f2w, pinw, poutw, x_t, cond };
        u16* dsts[NSEG] = { wq, wk, wv, wo, cwq, cwk, cwv, cwo,
                            w1, w2, wpi, wpo, xtb, cdb };
        const int n4s[NSEG] = { NW4, NW4, NW4, NW4, NW4, NW4, NW4, NW4,
                                NF4, NF4, DD * LATD / 4, LATD * DD / 4,
                                M * LATD / 4, BB * LCC * DD / 4 };
        int acc = 0;
        for (int i = 0; i < NSEG; i++) {
            a.src[i] = srcs[i]; a.dst[i] = dsts[i]; a.n4[i] = n4s[i];
            a.beg[i] = acc; acc += (n4s[i] + 255) / 256;
        }
        a.beg[NSEG] = acc;
        k_cvtm<<<acc, T256, 0, stream>>>(a);
    }

    // ---- time embedding path ----
    k_emb<<<(BB * DD + 255) / 256, 256, 0, stream>>>(tarr, emb);
    k_wlin<<<(BB * DFFN) / 4, T256, 0, stream>>>(emb, DD, tm1w, tm1b, h1t, DFFN, 2);
    k_wlin<<<(BB * DD) / 4,   T256, 0, stream>>>(h1t, DFFN, tm2w, tm2b, te, DD, 0);
    k_wlin<<<(BB * DD) / 4,   T256, 0, stream>>>(te, DD, ttw, ttb, ttv, DD, 0);

    // ---- all-layer cross K: kbc6[L] = cond @ ckw[L]^T  (z = layer) ----
    k_g<32, 64, u16, false><<<dim3(DD / 64, (BB * LCC) / 32, NLAYER), T256, 0, stream>>>(
        cdb, 0, 0, DD, cwk, nullptr, nullptr, 0, (long long)DD * DD, DD,
        kbc6, nullptr, nullptr, 0, (long long)BB * LCC * DD, DD,
        DD, NLAYER, 1.0f, nullptr, nullptr, 0, 0, 0.0f, nullptr, 0, 0, 0, 0, 0, 0, 0);
    // ---- all-layer cross V (transposed): vcT6[L] ----
    k_g<32, 64, u16, false><<<dim3(DD / 64, (BB * LCC) / 32, NLAYER), T256, 0, stream>>>(
        cdb, 0, 0, DD, cwv, nullptr, nullptr, 0, (long long)DD * DD, DD,
        vcT6, nullptr, nullptr, 0, (long long)BB * HH * HD * LCC, DD,
        DD, NLAYER, 1.0f, nullptr, nullptr, 0, 0, 0.0f, nullptr, 0, 0, 0,
        /*wt=*/1, /*shift=*/7, /*sbT=*/ZWT, /*ldct=*/LCC);

    // ---- input projection: h = x_t @ pinw.T + pinb + ttv[b] ----
    k_g<32, 64, float, false><<<dim3(DD / 64, M / 32, 1), T256, 0, stream>>>(
        xtb, 0, 0, LATD, wpi, nullptr, nullptr, 0, 0, LATD,
        h, nullptr, nullptr, 0, 0, DD,
        LATD, 1, 1.0f, pinb, ttv, DD, 9, 0.0f, nullptr, 0, 0, 0, 0, 0, 0, 0);

    for (int L = 0; L < NLAYER; L++) {
        const size_t LW = (size_t)L * DD * DD;

        // ======== self-attention with QGFD ========
        k_ln<<<M / 4, LN_B, 0, stream>>>(h, xn, n1g + (size_t)L * DD, n1b + (size_t)L * DD);

        // fused QKV (z: 0=q, 1=k, 2=v transposed)
        k_g<64, 64, u16, true><<<dim3(DD / 64, M / 64, 3), T256, 0, stream>>>(
            xn, 0, 0, DD, wq + LW, wk + LW, wv + LW, 0, 0, DD,
            qb, kb, vbT, 0, 0, DD,
            DD, 1, 1.0f, nullptr, nullptr, 0, 0, 0.0f, nullptr, 0, 0, 0,
            /*wt_mask=*/4, /*wt_shift=*/9, /*sbT=*/ZVT, /*ldct=*/LQQ);

        // fused S+softmax+P-write+ubT (QGFD first propagation)
        k_attn<true><<<dim3(1, LQQ / 64, BB * HH), T256, 0, stream>>>(
            qb, kb, vbT, P, ubT, nullptr, 0.125f);

        // ob = P @ ub (second propagation)
        k_g<32, 64, u16, false><<<dim3(1, LQQ / 32, BB * HH), T256, 0, stream>>>(
            P, (long long)HH * ZS, ZS, LQQ, ubT, nullptr, nullptr, ZVT, ZVH, LQQ,
            ob, nullptr, nullptr, ZA, 64, DD,
            LQQ, HH, 1.0f, nullptr, nullptr, 0, 0, 0.0f, nullptr, 0, 0, 0, 0, 0, 0, 0);

        // h += ob @ ow.T + obias
        k_g<32, 64, float, false><<<dim3(DD / 64, M / 32, 1), T256, 0, stream>>>(
            ob, 0, 0, DD, wo + LW, nullptr, nullptr, 0, 0, DD,
            h, nullptr, nullptr, 0, 0, DD,
            DD, 1, 1.0f, sa_ob + (size_t)L * DD, h, DD, 0, 0.0f, nullptr, 0, 0, 0, 0, 0, 0, 0);

        // ======== cross-attention ========
        k_ln<<<M / 4, LN_B, 0, stream>>>(h, xn, n2g + (size_t)L * DD, n2b + (size_t)L * DD);

        k_g<32, 64, u16, false><<<dim3(DD / 64, M / 32, 1), T256, 0, stream>>>(
            xn, 0, 0, DD, cwq + LW, nullptr, nullptr, 0, 0, DD,
            qb, nullptr, nullptr, 0, 0, DD,
            DD, 1, 1.0f, nullptr, nullptr, 0, 0, 0.0f, nullptr, 0, 0, 0, 0, 0, 0, 0);

        // fused Sc+mask+softmax+Pc@vc -> ob
        k_attn<false><<<dim3(1, LQQ / 64, BB * HH), T256, 0, stream>>>(
            qb, kbc6 + (size_t)L * BB * LCC * DD, vcT6 + (size_t)L * BB * HH * HD * LCC,
            nullptr, ob, cmask, 0.125f);

        // h += ob @ cow.T + cob
        k_g<32, 64, float, false><<<dim3(DD / 64, M / 32, 1), T256, 0, stream>>>(
            ob, 0, 0, DD, cwo + LW, nullptr, nullptr, 0, 0, DD,
            h, nullptr, nullptr, 0, 0, DD,
            DD, 1, 1.0f, ca_ob + (size_t)L * DD, h, DD, 0, 0.0f, nullptr, 0, 0, 0, 0, 0, 0, 0);

        // ======== FFN ========
        k_ln<<<M / 4, LN_B, 0, stream>>>(h, xn, n3g + (size_t)L * DD, n3b + (size_t)L * DD);

        k_g<64, 64, u16, false><<<dim3(DFFN / 64, M / 64, 1), T256, 0, stream>>>(
            xn, 0, 0, DD, w1 + (size_t)L * DFFN * DD, nullptr, nullptr, 0, 0, DD,
            a1, nullptr, nullptr, 0, 0, DFFN,
            DD, 1, 1.0f, f1b + (size_t)L * DFFN, nullptr, 0, 0, 0.0f, nullptr, 0, 0,
            /*act=*/1, 0, 0, 0, 0);
        k_g<32, 64, float, false><<<dim3(DD / 64, M / 32, 1), T256, 0, stream>>>(
            a1, 0, 0, DFFN, w2 + (size_t)L * DD * DFFN, nullptr, nullptr, 0, 0, DFFN,
            h, nullptr, nullptr, 0, 0, DD,
            DFFN, 1, 1.0f, f2b + (size_t)L * DD, h, DD, 0, 0.0f, nullptr, 0, 0, 0, 0, 0, 0, 0);
    }

    // ---- final LN + output projection ----
    k_ln<<<M / 4, LN_B, 0, stream>>>(h, xn, fng, fnb);
    k_g<32, 32, float, false><<<dim3(LATD / 32, M / 32, 1), T256, 0, stream>>>(
        xn, 0, 0, DD, wpo, nullptr, nullptr, 0, 0, DD,
        (float*)d_out, nullptr, nullptr, 0, 0, LATD,
        DD, 1, 1.0f, poutb, nullptr, 0, 0, 0.0f, nullptr, 0, 0, 0, 0, 0, 0, 0);
}